// Round 8
// baseline (746.702 us; speedup 1.0000x reference)
//
#include <hip/hip_runtime.h>
#include <cstdint>
#include <cstddef>

// ---------- types / helpers ----------
using f32x4 = __attribute__((ext_vector_type(4))) float;
using bf16x8 = __attribute__((ext_vector_type(8))) __bf16;
using u16x4 = __attribute__((ext_vector_type(4))) unsigned short;
using u16x8 = __attribute__((ext_vector_type(8))) unsigned short;

#define DEV __device__ __forceinline__

DEV unsigned short f2b(float f) {
  __bf16 h = (__bf16)f;               // native v_cvt (RNE)
  return __builtin_bit_cast(unsigned short, h);
}
DEV float b2f(unsigned short u) {
  uint32_t w = ((uint32_t)u) << 16;
  return __builtin_bit_cast(float, w);
}

// async global->LDS, 16B per lane. LDS dest must be wave-uniform base + lane*16.
DEV void gload16(const unsigned short* g, unsigned short* l) {
  __builtin_amdgcn_global_load_lds(
      (const __attribute__((address_space(1))) void*)g,
      (__attribute__((address_space(3))) void*)l, 16, 0, 0);
}

// Problem constants
// B=8, C=256, H=W=128, HEADS=8, hd=32, WS=8, SHIFT=4, nW=256, tokens=131072

// ---------- all weight casts fp32 -> bf16, one launch ----------
__global__ void swin_cvt_all(const float* __restrict__ qkvw, const float* __restrict__ projw,
                             const float* __restrict__ fc1w, const float* __restrict__ fc2w,
                             unsigned short* __restrict__ wq, unsigned short* __restrict__ wp,
                             unsigned short* __restrict__ w1, unsigned short* __restrict__ w2) {
  int i = blockIdx.x * 256 + threadIdx.x;           // 0 .. 786431
  if (i < 196608) wq[i] = f2b(qkvw[i]);
  else if (i < 262144) wp[i - 196608] = f2b(projw[i - 196608]);
  else if (i < 524288) w1[i - 262144] = f2b(fc1w[i - 262144]);
  else w2[i - 524288] = f2b(fc2w[i - 524288]);
}

// ---------- precomputed attention bias+mask table ----------
// bt[cls][head][n][m] = rel_bias + (-100 if masked); cls: bit1=bottom-edge, bit0=right-edge
__global__ void swin_btab(const float* __restrict__ relb, float* __restrict__ bt) {
  int id = blockIdx.x * 256 + threadIdx.x;          // 0 .. 131071
  int m = id & 63, n = (id >> 6) & 63, head = (id >> 12) & 7, cls = id >> 15;
  bool eh = cls & 2, ew = cls & 1;
  int nh = n >> 3, nw = n & 7, mh = m >> 3, mw = m & 7;
  int rn = (eh ? ((nh >> 2) + 1) : 0) * 3 + (ew ? ((nw >> 2) + 1) : 0);
  int rm = (eh ? ((mh >> 2) + 1) : 0) * 3 + (ew ? ((mw >> 2) + 1) : 0);
  float v = relb[(size_t)((nh - mh + 7) * 15 + (nw - mw + 7)) * 8 + head];
  if (rn != rm) v -= 100.f;
  bt[id] = v;
}

// ---------- fused LN1: stats + normalize + shift + window partition + xb emit ----------
// Coalesced-write version: x tile transposed through LDS so stores are
// 256 B-contiguous per 32 lanes (r7 had 8B stores @512B stride -> 2.6x write amp).
__global__ __launch_bounds__(256)
void swin_ln1win(const float* __restrict__ x,
                 const float* __restrict__ lw, const float* __restrict__ lb,
                 unsigned short* __restrict__ win, unsigned short* __restrict__ xb) {
  __shared__ float sh[512];
  __shared__ float mean_[128], rstd_[128];
  __shared__ unsigned short tile[128 * 134];   // [w][c-half], pad 134 keeps reads 2-way
  int bh = blockIdx.x; int b = bh >> 7, h = bh & 127;
  int t = threadIdx.x;
  int w = t & 127, ch = t >> 7;
  const float* px = x + (((size_t)(b * 256 + ch * 128)) << 14) + (h << 7) + w;
  float s = 0.f, s2 = 0.f;
  for (int c = 0; c < 128; ++c) {
    float v = px[(size_t)c << 14];
    s += v; s2 += v * v;
  }
  sh[t] = s; sh[256 + t] = s2;
  __syncthreads();
  if (ch == 0) {
    s += sh[t + 128]; s2 += sh[256 + t + 128];
    float mu = s * (1.f / 256.f);
    mean_[w] = mu;
    rstd_[w] = rsqrtf(s2 * (1.f / 256.f) - mu * mu + 1e-5f);
  }
  int hp = (h + 124) & 127;           // shifted row coord
  int whh = hp >> 3, nh = hp & 7;
  int lg = t & 31, grp = t >> 5;
#pragma unroll
  for (int half = 0; half < 2; ++half) {
    int c0 = half << 7;
    __syncthreads();                  // stats visible / tile reusable
    // load x[c0+cr][w] -> tile[w][cr] (global coalesced; LDS write 2-way free)
#pragma unroll
    for (int i = 0; i < 64; ++i) {
      int cr = (i << 1) + ch;         // 0..127
      float v = x[(((size_t)(b * 256 + c0 + cr)) << 14) + (h << 7) + w];
      tile[w * 134 + cr] = f2b(v);
    }
    __syncthreads();
    // write phase: 32-lane group covers 128 consecutive channels of one token
#pragma unroll
    for (int i = 0; i < 16; ++i) {
      int w2 = (i << 3) + grp;
      u16x4 raw = *(const u16x4*)&tile[w2 * 134 + (lg << 2)];
      float mu = mean_[w2], rs = rstd_[w2];
      int c = c0 + (lg << 2);
      f32x4 lwv = *(const f32x4*)(lw + c);
      f32x4 lbv = *(const f32x4*)(lb + c);
      u16x4 o;
#pragma unroll
      for (int k = 0; k < 4; ++k)
        o[k] = f2b((b2f(raw[k]) - mu) * rs * lwv[k] + lbv[k]);
      int wp_ = (w2 + 124) & 127;
      int wwc = wp_ >> 3, nw = wp_ & 7;
      size_t wt = (size_t)b * 256 + whh * 16 + wwc;
      int n = (nh << 3) + nw;
      *(u16x4*)&win[((wt << 6) + n) * 256 + c] = o;
      *(u16x4*)&xb[(((size_t)bh << 7) + w2) * 256 + c] = raw;
    }
  }
}

// ---------- bf16 GEMM: C = A(M,K) @ W(N,K)^T, 256x256 tile, 8 waves ----------
// M-strip persistent pipeline: each block runs MSTRIP M-tiles through ONE flat
// tau-pipeline (prologue paid once; epilogue of tile ms overlaps in-flight
// stages of ms+1). Counted vmcnt(8) stays safe across the epilogue: stage(tau)
// ops precede epilogue ops in issue order. BK=64, 2 kk-phases per K-tile,
// 2-dbuf LDS 128 KB, XOR-8 swizzle (0 conflicts verified), setprio on MFMA.
// MODE 0: QKV  -> bf16 (ld 768), bias, scale q-part           [swapped: 4 cols/lane reg]
// MODE 1: PROJ -> bf16 T token-major, bias + xb shortcut      [swapped]
// MODE 2: FC1  -> bf16 h2 (ld 1024), bias + gelu              [swapped]
// MODE 3: FC2  -> fp32 d_out NCHW, bias + T(bf16) residual    [unswapped: 4 rows/lane reg]
template<int MODE, int KTOT, int MSTRIP>
__global__ __launch_bounds__(512, 2)
void swin_gemm(const unsigned short* __restrict__ A,
               const unsigned short* __restrict__ Wt,
               const float* __restrict__ bias,
               void* __restrict__ outp,
               const void* __restrict__ extra,
               int M, int N) {
  constexpr int KT = KTOT / 64;
  constexpr int NT = KT * MSTRIP;
  __shared__ __align__(16) unsigned short As[2][16384];  // 2 x 256rows x 64cols
  __shared__ __align__(16) unsigned short Bs[2][16384];
  // XCD-chunked swizzle (grid % 8 == 0)
  const int cpx = gridDim.x >> 3;
  const int bid = (blockIdx.x & 7) * cpx + (blockIdx.x >> 3);
  const int nbn = N >> 8;
  const int bms = bid / nbn;
  const int bn = bid % nbn;
  const int m_base = bms * (256 * MSTRIP), n0 = bn << 8;
  const int t = threadIdx.x;
  const int lane = t & 63;
  const int wave = t >> 6;
  const int wr = wave >> 2, wc = wave & 3;   // 2M x 4N, wave tile 128x64
  const int cl = lane & 15, g = lane >> 4;

  const int trow = t >> 3;                   // 0..63
  const int ks = (t & 7) ^ (trow & 7);
  const unsigned short* agb0 = A  + (size_t)(m_base + trow) * KTOT + ks * 8;
  const unsigned short* bgb  = Wt + (size_t)(n0 + trow) * KTOT + ks * 8;

  const int ra = wr * 128 + cl;              // + i*16
  const int rb = wc * 64 + cl;               // + j*16
  const int ka0 = (g ^ (cl & 7)) * 8;        // kk=1: ^ 32 elems

  auto stage = [&](int buf, int tau) {
    const int mt = tau / KT;
    const int ko = (tau % KT) * 64;
    const unsigned short* ag = agb0 + (size_t)mt * 256 * KTOT;
#pragma unroll
    for (int l = 0; l < 4; ++l) {
      gload16(ag  + (size_t)l * 64 * KTOT + ko, &As[buf][l * 4096 + t * 8]);
      gload16(bgb + (size_t)l * 64 * KTOT + ko, &Bs[buf][l * 4096 + t * 8]);
    }
  };

  f32x4 acc[8][4] = {};

  stage(0, 0);
  stage(1, 1);
#pragma unroll
  for (int ms = 0; ms < MSTRIP; ++ms) {
#pragma unroll
    for (int kt = 0; kt < KT; ++kt) {
      const int tau = ms * KT + kt;
      const int cur = tau & 1;
      if (tau + 1 < NT) asm volatile("s_waitcnt vmcnt(8)" ::: "memory");
      else              asm volatile("s_waitcnt vmcnt(0)" ::: "memory");
      __builtin_amdgcn_s_barrier();          // buf[cur] resident for all waves
#pragma unroll
      for (int kk = 0; kk < 2; ++kk) {
        const int ka = ka0 ^ (kk << 5);
        bf16x8 af[8], bf[4];
#pragma unroll
        for (int i = 0; i < 8; ++i)
          af[i] = *(const bf16x8*)&As[cur][(ra + i * 16) * 64 + ka];
#pragma unroll
        for (int j = 0; j < 4; ++j)
          bf[j] = *(const bf16x8*)&Bs[cur][(rb + j * 16) * 64 + ka];
        asm volatile("s_waitcnt lgkmcnt(0)" ::: "memory");
        __builtin_amdgcn_sched_barrier(0);
        if (kk == 1) {
          __builtin_amdgcn_s_barrier();      // all reads of buf[cur] done
          if (tau + 2 < NT) stage(cur, tau + 2);
        }
        __builtin_amdgcn_s_setprio(1);
#pragma unroll
        for (int i = 0; i < 8; ++i)
#pragma unroll
          for (int j = 0; j < 4; ++j) {
            if constexpr (MODE == 3)
              acc[i][j] = __builtin_amdgcn_mfma_f32_16x16x32_bf16(af[i], bf[j], acc[i][j], 0, 0, 0);
            else
              acc[i][j] = __builtin_amdgcn_mfma_f32_16x16x32_bf16(bf[j], af[i], acc[i][j], 0, 0, 0);
          }
        __builtin_amdgcn_s_setprio(0);
      }
    }

    // ---- epilogue for M-tile ms (overlaps next strip's in-flight stages) ----
    const int m0 = m_base + ms * 256;
    if constexpr (MODE == 3) {
      const unsigned short* Tb = (const unsigned short*)extra;
#pragma unroll
      for (int i = 0; i < 8; ++i) {
        int rowb = m0 + wr * 128 + i * 16 + (g << 2);
        int b = rowb >> 14, hw = rowb & 16383;
#pragma unroll
        for (int j = 0; j < 4; ++j) {
          int col = n0 + wc * 64 + j * 16 + cl;
          float bs = bias[col];
          f32x4 vv;
#pragma unroll
          for (int r = 0; r < 4; ++r)
            vv[r] = acc[i][j][r] + bs + b2f(Tb[((size_t)(rowb + r) << 8) + col]);
          *(f32x4*)&((float*)outp)[(((size_t)(b << 8) + col) << 14) + hw] = vv;
        }
      }
    } else {
#pragma unroll
      for (int i = 0; i < 8; ++i) {
        int row = m0 + wr * 128 + i * 16 + cl;
#pragma unroll
        for (int j = 0; j < 4; ++j) {
          int colb = n0 + wc * 64 + j * 16 + (g << 2);
          f32x4 b4 = *(const f32x4*)(bias + colb);
          if constexpr (MODE == 0) {
            const bool qs = (n0 == 0);
            u16x4 o;
#pragma unroll
            for (int r = 0; r < 4; ++r) {
              float v = acc[i][j][r] + b4[r];
              if (qs) v *= 0.17677669529663687f;  // 1/sqrt(32)
              o[r] = f2b(v);
            }
            *(u16x4*)((unsigned short*)outp + (size_t)row * 768 + colb) = o;
          } else if constexpr (MODE == 1) {
            u16x4 xv = *(const u16x4*)((const unsigned short*)extra + (size_t)row * 256 + colb);
            u16x4 o;
#pragma unroll
            for (int r = 0; r < 4; ++r)
              o[r] = f2b(acc[i][j][r] + b4[r] + b2f(xv[r]));
            *(u16x4*)((unsigned short*)outp + (size_t)row * 256 + colb) = o;
          } else {  // MODE 2: FC1 + gelu(tanh): v * sigmoid(2u)
            u16x4 o;
#pragma unroll
            for (int r = 0; r < 4; ++r) {
              float v = acc[i][j][r] + b4[r];
              float p = v * fmaf(v * v, -0.0713548256f, -1.5957691216f);  // -2u
              float e = __expf(p);
              o[r] = f2b(v * __builtin_amdgcn_rcpf(1.f + e));
            }
            *(u16x4*)((unsigned short*)outp + (size_t)row * 1024 + colb) = o;
          }
        }
      }
    }
    if (ms + 1 < MSTRIP) {
#pragma unroll
      for (int i = 0; i < 8; ++i)
#pragma unroll
        for (int j = 0; j < 4; ++j)
          acc[i][j] = f32x4{0.f, 0.f, 0.f, 0.f};
    }
  }
}

// ---------- windowed attention: one block = (window, 4 heads), 1 wave/head ----------
// Bias+mask from precomputed table (f32x4 loads). Output in TOKEN order.
__global__ __launch_bounds__(256)
void swin_attn(const unsigned short* __restrict__ qkv,
               const float* __restrict__ btab,
               unsigned short* __restrict__ attn_out) {
  __shared__ unsigned short Plds[4][64 * 68];
  __shared__ unsigned short Vlds[4][32 * 68];
  int bid = blockIdx.x;
  int w = bid >> 1, hg = bid & 1;
  int t = threadIdx.x;
  int wave = t >> 6, lane = t & 63;
  int head = (hg << 2) + wave;
  int cl = lane & 15, g = lane >> 4;
  const size_t wb = (size_t)w * 64 * 768;

  bf16x8 qf[4], kf[4];
#pragma unroll
  for (int ni = 0; ni < 4; ++ni) {
    int n = (ni << 4) + cl;
    qf[ni] = *(const bf16x8*)(qkv + wb + (size_t)n * 768 + (head << 5) + (g << 3));
    kf[ni] = *(const bf16x8*)(qkv + wb + (size_t)n * 768 + 256 + (head << 5) + (g << 3));
  }

  f32x4 s[4][4] = {};
#pragma unroll
  for (int mi = 0; mi < 4; ++mi)
#pragma unroll
    for (int ni = 0; ni < 4; ++ni)
      s[mi][ni] = __builtin_amdgcn_mfma_f32_16x16x32_bf16(kf[mi], qf[ni], s[mi][ni], 0, 0, 0);

#pragma unroll
  for (int c = 0; c < 4; ++c) {
    int id = (c << 6) + lane;
    int m = id >> 2, dc = (id & 3) << 3;
    u16x8 vv = *(const u16x8*)(qkv + wb + (size_t)m * 768 + 512 + (head << 5) + dc);
#pragma unroll
    for (int j = 0; j < 8; ++j)
      Vlds[wave][(dc + j) * 68 + m] = vv[j];
  }

  int wi = w & 255;
  int cls = (((wi >> 4) == 15) ? 2 : 0) + (((wi & 15) == 15) ? 1 : 0);
  const float* bt = btab + (((size_t)(cls << 3) + head) << 12);
#pragma unroll
  for (int ni = 0; ni < 4; ++ni) {
    int n = (ni << 4) + cl;
    float mx = -1e30f;
#pragma unroll
    for (int mi = 0; mi < 4; ++mi) {
      f32x4 bb = *(const f32x4*)&bt[n * 64 + (mi << 4) + (g << 2)];
#pragma unroll
      for (int r = 0; r < 4; ++r) {
        float v = s[mi][ni][r] + bb[r];
        s[mi][ni][r] = v;
        mx = fmaxf(mx, v);
      }
    }
    mx = fmaxf(mx, __shfl_xor(mx, 16));
    mx = fmaxf(mx, __shfl_xor(mx, 32));
    float sum = 0.f;
#pragma unroll
    for (int mi = 0; mi < 4; ++mi)
#pragma unroll
      for (int r = 0; r < 4; ++r) {
        float p = __expf(s[mi][ni][r] - mx);
        s[mi][ni][r] = p;
        sum += p;
      }
    sum += __shfl_xor(sum, 16);
    sum += __shfl_xor(sum, 32);
    float inv = __builtin_amdgcn_rcpf(sum);
#pragma unroll
    for (int mi = 0; mi < 4; ++mi) {
      u16x4 pk;
#pragma unroll
      for (int r = 0; r < 4; ++r) pk[r] = f2b(s[mi][ni][r] * inv);
      *(u16x4*)&Plds[wave][n * 68 + (mi << 4) + (g << 2)] = pk;
    }
  }
  __syncthreads();

  union FragU { bf16x8 v; uint64_t q[2]; };
  f32x4 o[4][2] = {};
#pragma unroll
  for (int mt = 0; mt < 2; ++mt) {
    FragU vf[2];
#pragma unroll
    for (int dt = 0; dt < 2; ++dt) {
      int d = (dt << 4) + cl;
      const unsigned short* p = &Vlds[wave][d * 68 + (mt << 5) + (g << 3)];
      vf[dt].q[0] = *(const uint64_t*)p;
      vf[dt].q[1] = *(const uint64_t*)(p + 4);
    }
#pragma unroll
    for (int ni = 0; ni < 4; ++ni) {
      FragU pa;
      const unsigned short* pp = &Plds[wave][((ni << 4) + cl) * 68 + (mt << 5) + (g << 3)];
      pa.q[0] = *(const uint64_t*)pp;
      pa.q[1] = *(const uint64_t*)(pp + 4);
#pragma unroll
      for (int dt = 0; dt < 2; ++dt)
        o[ni][dt] = __builtin_amdgcn_mfma_f32_16x16x32_bf16(pa.v, vf[dt].v, o[ni][dt], 0, 0, 0);
    }
  }

  int b = w >> 8;
#pragma unroll
  for (int ni = 0; ni < 4; ++ni)
#pragma unroll
    for (int dt = 0; dt < 2; ++dt)
#pragma unroll
      for (int r = 0; r < 4; ++r) {
        int n = (ni << 4) + (g << 2) + r;
        int d = (dt << 4) + cl;
        int hs = ((wi >> 4) << 3) + (n >> 3), ws_ = ((wi & 15) << 3) + (n & 7);
        int hh = (hs + 4) & 127, ww = (ws_ + 4) & 127;
        size_t tok = ((size_t)b << 14) + (hh << 7) + ww;
        attn_out[tok * 256 + (head << 5) + d] = f2b(o[ni][dt][r]);
      }
}

// ---------- fused LN2: stats + normalize, T bf16 in -> tn bf16 out ----------
__global__ void swin_ln2_fused(const unsigned short* __restrict__ Tb,
                               const float* __restrict__ lw, const float* __restrict__ lb,
                               unsigned short* __restrict__ tn) {
  int tok = (blockIdx.x << 2) + (threadIdx.x >> 6);
  int lane = threadIdx.x & 63;
  u16x4 tv = *(const u16x4*)(Tb + ((size_t)tok << 8) + (lane << 2));
  f32x4 v;
#pragma unroll
  for (int j = 0; j < 4; ++j) v[j] = b2f(tv[j]);
  float s = v[0] + v[1] + v[2] + v[3];
  float s2 = v[0] * v[0] + v[1] * v[1] + v[2] * v[2] + v[3] * v[3];
#pragma unroll
  for (int off = 32; off > 0; off >>= 1) {
    s += __shfl_xor(s, off);
    s2 += __shfl_xor(s2, off);
  }
  float mean = s * (1.f / 256.f);
  float rstd = rsqrtf(s2 * (1.f / 256.f) - mean * mean + 1e-5f);
  f32x4 wv = *(const f32x4*)(lw + (lane << 2));
  f32x4 bv = *(const f32x4*)(lb + (lane << 2));
  u16x4 o;
#pragma unroll
  for (int j = 0; j < 4; ++j) o[j] = f2b((v[j] - mean) * rstd * wv[j] + bv[j]);
  *(u16x4*)(tn + ((size_t)tok << 8) + (lane << 2)) = o;
}

// ---------- launch ----------
extern "C" void kernel_launch(void* const* d_in, const int* in_sizes, int n_in,
                              void* d_out, int out_size, void* d_ws, size_t ws_size,
                              hipStream_t stream) {
  const float* x    = (const float*)d_in[0];
  const float* ln1w = (const float*)d_in[1];
  const float* ln1b = (const float*)d_in[2];
  const float* qkvw = (const float*)d_in[3];
  const float* qkvb = (const float*)d_in[4];
  const float* relb = (const float*)d_in[5];
  const float* projw = (const float*)d_in[6];
  const float* projb = (const float*)d_in[7];
  const float* ln2w = (const float*)d_in[8];
  const float* ln2b = (const float*)d_in[9];
  const float* fc1w = (const float*)d_in[10];
  const float* fc1b = (const float*)d_in[11];
  const float* fc2w = (const float*)d_in[12];
  const float* fc2b = (const float*)d_in[13];

  char* ws = (char*)d_ws;
  unsigned short* win = (unsigned short*)(ws);                  // 67,108,864 B
  unsigned short* qkv = (unsigned short*)(ws + 67108864);       // 201,326,592 B
  unsigned short* T   = (unsigned short*)(ws + 268435456);      // 67,108,864 B
  unsigned short* xb  = (unsigned short*)(ws + 335544320);      // 67,108,864 B
  unsigned short* wq  = (unsigned short*)(ws + 402653184);      // 393,216 B
  unsigned short* wp  = (unsigned short*)(ws + 403046400);      // 131,072 B
  unsigned short* w1  = (unsigned short*)(ws + 403177472);      // 524,288 B
  unsigned short* w2  = (unsigned short*)(ws + 403701760);      // 524,288 B
  float* btab         = (float*)(ws + 404226048);               // 524,288 B -> end 404,750,336
  unsigned short* attn_out = win;                // reuse (win dead after QKV)
  unsigned short* h2  = (unsigned short*)(ws);   // 268 MB (win+qkv regions, dead after proj)
  unsigned short* tn  = (unsigned short*)d_out;  // 67 MB scratch inside d_out (overwritten by FC2)

  if (ws_size < 404750336ull) return;  // workspace too small: fail loudly (poison stays)

  swin_cvt_all<<<3072, 256, 0, stream>>>(qkvw, projw, fc1w, fc2w, wq, wp, w1, w2);
  swin_btab<<<512, 256, 0, stream>>>(relb, btab);
  swin_ln1win<<<1024, 256, 0, stream>>>(x, ln1w, ln1b, win, xb);
  swin_gemm<0, 256, 2><<<768, 512, 0, stream>>>(win, wq, qkvb, qkv, nullptr, 131072, 768);
  swin_attn<<<4096, 256, 0, stream>>>(qkv, btab, attn_out);
  swin_gemm<1, 256, 2><<<256, 512, 0, stream>>>(attn_out, wp, projb, T, xb, 131072, 256);
  swin_ln2_fused<<<32768, 256, 0, stream>>>(T, ln2w, ln2b, tn);
  swin_gemm<2, 256, 2><<<1024, 512, 0, stream>>>(tn, w1, fc1b, h2, nullptr, 131072, 1024);
  swin_gemm<3, 1024, 1><<<512, 512, 0, stream>>>(h2, w2, fc2b, d_out, T, 131072, 256);
}

// Round 9
// 664.179 us; speedup vs baseline: 1.1242x; 1.1242x over previous
//
#include <hip/hip_runtime.h>
#include <cstdint>
#include <cstddef>

// ---------- types / helpers ----------
using f32x4 = __attribute__((ext_vector_type(4))) float;
using bf16x8 = __attribute__((ext_vector_type(8))) __bf16;
using u16x4 = __attribute__((ext_vector_type(4))) unsigned short;
using u16x8 = __attribute__((ext_vector_type(8))) unsigned short;

#define DEV __device__ __forceinline__

DEV unsigned short f2b(float f) {
  __bf16 h = (__bf16)f;               // native v_cvt (RNE)
  return __builtin_bit_cast(unsigned short, h);
}
DEV float b2f(unsigned short u) {
  uint32_t w = ((uint32_t)u) << 16;
  return __builtin_bit_cast(float, w);
}

// async global->LDS, 16B per lane. LDS dest must be wave-uniform base + lane*16.
DEV void gload16(const unsigned short* g, unsigned short* l) {
  __builtin_amdgcn_global_load_lds(
      (const __attribute__((address_space(1))) void*)g,
      (__attribute__((address_space(3))) void*)l, 16, 0, 0);
}

// Problem constants
// B=8, C=256, H=W=128, HEADS=8, hd=32, WS=8, SHIFT=4, nW=256, tokens=131072

// ---------- all weight casts fp32 -> bf16, one launch ----------
__global__ void swin_cvt_all(const float* __restrict__ qkvw, const float* __restrict__ projw,
                             const float* __restrict__ fc1w, const float* __restrict__ fc2w,
                             unsigned short* __restrict__ wq, unsigned short* __restrict__ wp,
                             unsigned short* __restrict__ w1, unsigned short* __restrict__ w2) {
  int i = blockIdx.x * 256 + threadIdx.x;           // 0 .. 786431
  if (i < 196608) wq[i] = f2b(qkvw[i]);
  else if (i < 262144) wp[i - 196608] = f2b(projw[i - 196608]);
  else if (i < 524288) w1[i - 262144] = f2b(fc1w[i - 262144]);
  else w2[i - 524288] = f2b(fc2w[i - 524288]);
}

// ---------- precomputed attention bias+mask table ----------
// bt[cls][head][n][m] = rel_bias + (-100 if masked); cls: bit1=bottom-edge, bit0=right-edge
__global__ void swin_btab(const float* __restrict__ relb, float* __restrict__ bt) {
  int id = blockIdx.x * 256 + threadIdx.x;          // 0 .. 131071
  int m = id & 63, n = (id >> 6) & 63, head = (id >> 12) & 7, cls = id >> 15;
  bool eh = cls & 2, ew = cls & 1;
  int nh = n >> 3, nw = n & 7, mh = m >> 3, mw = m & 7;
  int rn = (eh ? ((nh >> 2) + 1) : 0) * 3 + (ew ? ((nw >> 2) + 1) : 0);
  int rm = (eh ? ((mh >> 2) + 1) : 0) * 3 + (ew ? ((mw >> 2) + 1) : 0);
  float v = relb[(size_t)((nh - mh + 7) * 15 + (nw - mw + 7)) * 8 + head];
  if (rn != rm) v -= 100.f;
  bt[id] = v;
}

// ---------- fused LN1: stats + normalize + shift + window partition + xb emit ----------
// Coalesced-write version: x tile transposed through LDS so stores are
// 256 B-contiguous per 32 lanes.
__global__ __launch_bounds__(256)
void swin_ln1win(const float* __restrict__ x,
                 const float* __restrict__ lw, const float* __restrict__ lb,
                 unsigned short* __restrict__ win, unsigned short* __restrict__ xb) {
  __shared__ float sh[512];
  __shared__ float mean_[128], rstd_[128];
  __shared__ unsigned short tile[128 * 136];   // [w][c-half]; 272B rows keep u16x4 8B-aligned
  int bh = blockIdx.x; int b = bh >> 7, h = bh & 127;
  int t = threadIdx.x;
  int w = t & 127, ch = t >> 7;
  const float* px = x + (((size_t)(b * 256 + ch * 128)) << 14) + (h << 7) + w;
  float s = 0.f, s2 = 0.f;
  for (int c = 0; c < 128; ++c) {
    float v = px[(size_t)c << 14];
    s += v; s2 += v * v;
  }
  sh[t] = s; sh[256 + t] = s2;
  __syncthreads();
  if (ch == 0) {
    s += sh[t + 128]; s2 += sh[256 + t + 128];
    float mu = s * (1.f / 256.f);
    mean_[w] = mu;
    rstd_[w] = rsqrtf(s2 * (1.f / 256.f) - mu * mu + 1e-5f);
  }
  int hp = (h + 124) & 127;           // shifted row coord
  int whh = hp >> 3, nh = hp & 7;
  int lg = t & 31, grp = t >> 5;
#pragma unroll
  for (int half = 0; half < 2; ++half) {
    int c0 = half << 7;
    __syncthreads();                  // stats visible / tile reusable
    // load x[c0+cr][w] -> tile[w][cr] (global coalesced)
#pragma unroll
    for (int i = 0; i < 64; ++i) {
      int cr = (i << 1) + ch;         // 0..127
      float v = x[(((size_t)(b * 256 + c0 + cr)) << 14) + (h << 7) + w];
      tile[w * 136 + cr] = f2b(v);
    }
    __syncthreads();
    // write phase: 32-lane group covers 128 consecutive channels of one token
#pragma unroll
    for (int i = 0; i < 16; ++i) {
      int w2 = (i << 3) + grp;
      u16x4 raw = *(const u16x4*)&tile[w2 * 136 + (lg << 2)];
      float mu = mean_[w2], rs = rstd_[w2];
      int c = c0 + (lg << 2);
      f32x4 lwv = *(const f32x4*)(lw + c);
      f32x4 lbv = *(const f32x4*)(lb + c);
      u16x4 o;
#pragma unroll
      for (int k = 0; k < 4; ++k)
        o[k] = f2b((b2f(raw[k]) - mu) * rs * lwv[k] + lbv[k]);
      int wp_ = (w2 + 124) & 127;
      int wwc = wp_ >> 3, nw = wp_ & 7;
      size_t wt = (size_t)b * 256 + whh * 16 + wwc;
      int n = (nh << 3) + nw;
      *(u16x4*)&win[((wt << 6) + n) * 256 + c] = o;
      *(u16x4*)&xb[(((size_t)bh << 7) + w2) * 256 + c] = raw;
    }
  }
}

// ---------- bf16 GEMM: C = A(M,K) @ W(N,K)^T, 256x256 tile, 8 waves ----------
// r7 pipeline (best measured): BK=64, 2-dbuf LDS (128 KB), counted vmcnt(8)
// with 2 K-tiles in flight, drain only at tail; 2 kk-phases per K-tile of
// {12 ds_read -> lgkm0 -> 32 MFMA}; XOR-8 swizzle (verified 0 conflicts);
// setprio around MFMA cluster.
// MODE 0: QKV  -> bf16 (ld 768), bias, scale q-part           [swapped: 4 cols/lane reg]
// MODE 1: PROJ -> bf16 T token-major + FUSED LN2 -> tn bf16   [swapped]
// MODE 2: FC1  -> bf16 h2 (ld 1024), bias + gelu              [swapped]
// MODE 3: FC2  -> fp32 d_out NCHW, bias + T(bf16) residual    [unswapped: 4 rows/lane reg]
template<int MODE, int KTOT>
__global__ __launch_bounds__(512, 2)
void swin_gemm(const unsigned short* __restrict__ A,
               const unsigned short* __restrict__ Wt,
               const float* __restrict__ bias,
               void* __restrict__ outp,
               const void* __restrict__ extra,
               int M, int N,
               const float* __restrict__ lw2 = nullptr,
               const float* __restrict__ lb2 = nullptr,
               unsigned short* __restrict__ tn = nullptr) {
  constexpr int KT = KTOT / 64;
  __shared__ __align__(16) unsigned short As[2][16384];  // 2 x 256rows x 64cols
  __shared__ __align__(16) unsigned short Bs[2][16384];
  // XCD-chunked swizzle (grid % 8 == 0)
  const int cpx = gridDim.x >> 3;
  const int bid = (blockIdx.x & 7) * cpx + (blockIdx.x >> 3);
  const int nbn = N >> 8;
  const int bm = bid / nbn;
  const int bn = bid % nbn;
  const int m0 = bm << 8, n0 = bn << 8;
  const int t = threadIdx.x;
  const int lane = t & 63;
  const int wave = t >> 6;
  const int wr = wave >> 2, wc = wave & 3;   // 2M x 4N, wave tile 128x64
  const int cl = lane & 15, g = lane >> 4;

  const int trow = t >> 3;                   // 0..63
  const int ks = (t & 7) ^ (trow & 7);
  const unsigned short* agb = A  + (size_t)(m0 + trow) * KTOT + ks * 8;
  const unsigned short* bgb = Wt + (size_t)(n0 + trow) * KTOT + ks * 8;

  const int ra = wr * 128 + cl;              // + i*16
  const int rb = wc * 64 + cl;               // + j*16
  const int ka0 = (g ^ (cl & 7)) * 8;        // kk=1: ^ 32 elems

  auto stage = [&](int buf, int kt) {
    const int ko = kt * 64;
#pragma unroll
    for (int l = 0; l < 4; ++l) {
      gload16(agb + (size_t)l * 64 * KTOT + ko, &As[buf][l * 4096 + t * 8]);
      gload16(bgb + (size_t)l * 64 * KTOT + ko, &Bs[buf][l * 4096 + t * 8]);
    }
  };

  f32x4 acc[8][4] = {};

  stage(0, 0);
  stage(1, 1);
#pragma unroll
  for (int kt = 0; kt < KT; ++kt) {
    const int cur = kt & 1;
    if (kt + 1 < KT) asm volatile("s_waitcnt vmcnt(8)" ::: "memory");
    else             asm volatile("s_waitcnt vmcnt(0)" ::: "memory");
    __builtin_amdgcn_s_barrier();            // buf[cur] resident for all waves
#pragma unroll
    for (int kk = 0; kk < 2; ++kk) {
      const int ka = ka0 ^ (kk << 5);
      bf16x8 af[8], bf[4];
#pragma unroll
      for (int i = 0; i < 8; ++i)
        af[i] = *(const bf16x8*)&As[cur][(ra + i * 16) * 64 + ka];
#pragma unroll
      for (int j = 0; j < 4; ++j)
        bf[j] = *(const bf16x8*)&Bs[cur][(rb + j * 16) * 64 + ka];
      asm volatile("s_waitcnt lgkmcnt(0)" ::: "memory");
      __builtin_amdgcn_sched_barrier(0);
      if (kk == 1) {
        __builtin_amdgcn_s_barrier();        // all reads of buf[cur] done
        if (kt + 2 < KT) stage(cur, kt + 2); // refill; stays in flight
      }
      __builtin_amdgcn_s_setprio(1);
#pragma unroll
      for (int i = 0; i < 8; ++i)
#pragma unroll
        for (int j = 0; j < 4; ++j) {
          if constexpr (MODE == 3)
            acc[i][j] = __builtin_amdgcn_mfma_f32_16x16x32_bf16(af[i], bf[j], acc[i][j], 0, 0, 0);
          else
            acc[i][j] = __builtin_amdgcn_mfma_f32_16x16x32_bf16(bf[j], af[i], acc[i][j], 0, 0, 0);
        }
      __builtin_amdgcn_s_setprio(0);
    }
  }

  if constexpr (MODE == 3) {
    const unsigned short* Tb = (const unsigned short*)extra;
#pragma unroll
    for (int i = 0; i < 8; ++i) {
      int rowb = m0 + wr * 128 + i * 16 + (g << 2);
      int b = rowb >> 14, hw = rowb & 16383;
#pragma unroll
      for (int j = 0; j < 4; ++j) {
        int col = n0 + wc * 64 + j * 16 + cl;
        float bs = bias[col];
        f32x4 vv;
#pragma unroll
        for (int r = 0; r < 4; ++r)
          vv[r] = acc[i][j][r] + bs + b2f(Tb[((size_t)(rowb + r) << 8) + col]);
        *(f32x4*)&((float*)outp)[(((size_t)(b << 8) + col) << 14) + hw] = vv;
      }
    }
  } else if constexpr (MODE == 1) {
    // ---- proj + residual + FUSED LN2 ----
    // Block owns full rows (N=256 == one tile). acc <- T values; row stats via
    // shfl over g + cross-wave LDS partials; write T (bf16) and tn (normalized).
    float s[8], s2[8];
#pragma unroll
    for (int i = 0; i < 8; ++i) { s[i] = 0.f; s2[i] = 0.f; }
#pragma unroll
    for (int i = 0; i < 8; ++i) {
      int row = m0 + wr * 128 + i * 16 + cl;
#pragma unroll
      for (int j = 0; j < 4; ++j) {
        int colb = wc * 64 + j * 16 + (g << 2);
        f32x4 b4 = *(const f32x4*)(bias + colb);
        u16x4 xv = *(const u16x4*)((const unsigned short*)extra + (size_t)row * 256 + colb);
#pragma unroll
        for (int r = 0; r < 4; ++r) {
          float v = acc[i][j][r] + b4[r] + b2f(xv[r]);
          acc[i][j][r] = v;
          s[i] += v; s2[i] += v * v;
        }
      }
    }
#pragma unroll
    for (int i = 0; i < 8; ++i) {
      s[i]  += __shfl_xor(s[i], 16);  s[i]  += __shfl_xor(s[i], 32);
      s2[i] += __shfl_xor(s2[i], 16); s2[i] += __shfl_xor(s2[i], 32);
    }
    __syncthreads();                      // K-loop LDS traffic fully retired
    float* lsum = (float*)&As[0][0];      // [4][256] sums, [4][256] sumsq (8 KB)
    if (g == 0) {
#pragma unroll
      for (int i = 0; i < 8; ++i) {
        int rl = wr * 128 + i * 16 + cl;
        lsum[wc * 256 + rl] = s[i];
        lsum[1024 + wc * 256 + rl] = s2[i];
      }
    }
    __syncthreads();
#pragma unroll
    for (int i = 0; i < 8; ++i) {
      int rl = wr * 128 + i * 16 + cl;
      float ts = lsum[rl] + lsum[256 + rl] + lsum[512 + rl] + lsum[768 + rl];
      float ts2 = lsum[1024 + rl] + lsum[1280 + rl] + lsum[1536 + rl] + lsum[1792 + rl];
      float mu = ts * (1.f / 256.f);
      float rstd = rsqrtf(ts2 * (1.f / 256.f) - mu * mu + 1e-5f);
      int row = m0 + rl;
#pragma unroll
      for (int j = 0; j < 4; ++j) {
        int colb = wc * 64 + j * 16 + (g << 2);
        f32x4 wv = *(const f32x4*)(lw2 + colb);
        f32x4 bv = *(const f32x4*)(lb2 + colb);
        u16x4 oT, on;
#pragma unroll
        for (int r = 0; r < 4; ++r) {
          float v = acc[i][j][r];
          oT[r] = f2b(v);
          on[r] = f2b((v - mu) * rstd * wv[r] + bv[r]);
        }
        *(u16x4*)((unsigned short*)outp + (size_t)row * 256 + colb) = oT;
        *(u16x4*)(tn + (size_t)row * 256 + colb) = on;
      }
    }
  } else {
#pragma unroll
    for (int i = 0; i < 8; ++i) {
      int row = m0 + wr * 128 + i * 16 + cl;
#pragma unroll
      for (int j = 0; j < 4; ++j) {
        int colb = n0 + wc * 64 + j * 16 + (g << 2);
        f32x4 b4 = *(const f32x4*)(bias + colb);
        if constexpr (MODE == 0) {
          const bool qs = (n0 == 0);
          u16x4 o;
#pragma unroll
          for (int r = 0; r < 4; ++r) {
            float v = acc[i][j][r] + b4[r];
            if (qs) v *= 0.17677669529663687f;  // 1/sqrt(32)
            o[r] = f2b(v);
          }
          *(u16x4*)((unsigned short*)outp + (size_t)row * 768 + colb) = o;
        } else {  // MODE 2: FC1 + gelu(tanh): v * sigmoid(2u)
          u16x4 o;
#pragma unroll
          for (int r = 0; r < 4; ++r) {
            float v = acc[i][j][r] + b4[r];
            float p = v * fmaf(v * v, -0.0713548256f, -1.5957691216f);  // -2u
            float e = __expf(p);
            o[r] = f2b(v * __builtin_amdgcn_rcpf(1.f + e));
          }
          *(u16x4*)((unsigned short*)outp + (size_t)row * 1024 + colb) = o;
        }
      }
    }
  }
}

// ---------- windowed attention: one block = (window, 4 heads), 1 wave/head ----------
// Bias+mask from precomputed table (f32x4 loads). Output in TOKEN order.
__global__ __launch_bounds__(256)
void swin_attn(const unsigned short* __restrict__ qkv,
               const float* __restrict__ btab,
               unsigned short* __restrict__ attn_out) {
  __shared__ unsigned short Plds[4][64 * 68];
  __shared__ unsigned short Vlds[4][32 * 68];
  int bid = blockIdx.x;
  int w = bid >> 1, hg = bid & 1;
  int t = threadIdx.x;
  int wave = t >> 6, lane = t & 63;
  int head = (hg << 2) + wave;
  int cl = lane & 15, g = lane >> 4;
  const size_t wb = (size_t)w * 64 * 768;

  bf16x8 qf[4], kf[4];
#pragma unroll
  for (int ni = 0; ni < 4; ++ni) {
    int n = (ni << 4) + cl;
    qf[ni] = *(const bf16x8*)(qkv + wb + (size_t)n * 768 + (head << 5) + (g << 3));
    kf[ni] = *(const bf16x8*)(qkv + wb + (size_t)n * 768 + 256 + (head << 5) + (g << 3));
  }

  f32x4 s[4][4] = {};
#pragma unroll
  for (int mi = 0; mi < 4; ++mi)
#pragma unroll
    for (int ni = 0; ni < 4; ++ni)
      s[mi][ni] = __builtin_amdgcn_mfma_f32_16x16x32_bf16(kf[mi], qf[ni], s[mi][ni], 0, 0, 0);

#pragma unroll
  for (int c = 0; c < 4; ++c) {
    int id = (c << 6) + lane;
    int m = id >> 2, dc = (id & 3) << 3;
    u16x8 vv = *(const u16x8*)(qkv + wb + (size_t)m * 768 + 512 + (head << 5) + dc);
#pragma unroll
    for (int j = 0; j < 8; ++j)
      Vlds[wave][(dc + j) * 68 + m] = vv[j];
  }

  int wi = w & 255;
  int cls = (((wi >> 4) == 15) ? 2 : 0) + (((wi & 15) == 15) ? 1 : 0);
  const float* bt = btab + (((size_t)(cls << 3) + head) << 12);
#pragma unroll
  for (int ni = 0; ni < 4; ++ni) {
    int n = (ni << 4) + cl;
    float mx = -1e30f;
#pragma unroll
    for (int mi = 0; mi < 4; ++mi) {
      f32x4 bb = *(const f32x4*)&bt[n * 64 + (mi << 4) + (g << 2)];
#pragma unroll
      for (int r = 0; r < 4; ++r) {
        float v = s[mi][ni][r] + bb[r];
        s[mi][ni][r] = v;
        mx = fmaxf(mx, v);
      }
    }
    mx = fmaxf(mx, __shfl_xor(mx, 16));
    mx = fmaxf(mx, __shfl_xor(mx, 32));
    float sum = 0.f;
#pragma unroll
    for (int mi = 0; mi < 4; ++mi)
#pragma unroll
      for (int r = 0; r < 4; ++r) {
        float p = __expf(s[mi][ni][r] - mx);
        s[mi][ni][r] = p;
        sum += p;
      }
    sum += __shfl_xor(sum, 16);
    sum += __shfl_xor(sum, 32);
    float inv = __builtin_amdgcn_rcpf(sum);
#pragma unroll
    for (int mi = 0; mi < 4; ++mi) {
      u16x4 pk;
#pragma unroll
      for (int r = 0; r < 4; ++r) pk[r] = f2b(s[mi][ni][r] * inv);
      *(u16x4*)&Plds[wave][n * 68 + (mi << 4) + (g << 2)] = pk;
    }
  }
  __syncthreads();

  union FragU { bf16x8 v; uint64_t q[2]; };
  f32x4 o[4][2] = {};
#pragma unroll
  for (int mt = 0; mt < 2; ++mt) {
    FragU vf[2];
#pragma unroll
    for (int dt = 0; dt < 2; ++dt) {
      int d = (dt << 4) + cl;
      const unsigned short* p = &Vlds[wave][d * 68 + (mt << 5) + (g << 3)];
      vf[dt].q[0] = *(const uint64_t*)p;
      vf[dt].q[1] = *(const uint64_t*)(p + 4);
    }
#pragma unroll
    for (int ni = 0; ni < 4; ++ni) {
      FragU pa;
      const unsigned short* pp = &Plds[wave][((ni << 4) + cl) * 68 + (mt << 5) + (g << 3)];
      pa.q[0] = *(const uint64_t*)pp;
      pa.q[1] = *(const uint64_t*)(pp + 4);
#pragma unroll
      for (int dt = 0; dt < 2; ++dt)
        o[ni][dt] = __builtin_amdgcn_mfma_f32_16x16x32_bf16(pa.v, vf[dt].v, o[ni][dt], 0, 0, 0);
    }
  }

  int b = w >> 8;
#pragma unroll
  for (int ni = 0; ni < 4; ++ni)
#pragma unroll
    for (int dt = 0; dt < 2; ++dt)
#pragma unroll
      for (int r = 0; r < 4; ++r) {
        int n = (ni << 4) + (g << 2) + r;
        int d = (dt << 4) + cl;
        int hs = ((wi >> 4) << 3) + (n >> 3), ws_ = ((wi & 15) << 3) + (n & 7);
        int hh = (hs + 4) & 127, ww = (ws_ + 4) & 127;
        size_t tok = ((size_t)b << 14) + (hh << 7) + ww;
        attn_out[tok * 256 + (head << 5) + d] = f2b(o[ni][dt][r]);
      }
}

// ---------- launch ----------
extern "C" void kernel_launch(void* const* d_in, const int* in_sizes, int n_in,
                              void* d_out, int out_size, void* d_ws, size_t ws_size,
                              hipStream_t stream) {
  const float* x    = (const float*)d_in[0];
  const float* ln1w = (const float*)d_in[1];
  const float* ln1b = (const float*)d_in[2];
  const float* qkvw = (const float*)d_in[3];
  const float* qkvb = (const float*)d_in[4];
  const float* relb = (const float*)d_in[5];
  const float* projw = (const float*)d_in[6];
  const float* projb = (const float*)d_in[7];
  const float* ln2w = (const float*)d_in[8];
  const float* ln2b = (const float*)d_in[9];
  const float* fc1w = (const float*)d_in[10];
  const float* fc1b = (const float*)d_in[11];
  const float* fc2w = (const float*)d_in[12];
  const float* fc2b = (const float*)d_in[13];

  char* ws = (char*)d_ws;
  unsigned short* win = (unsigned short*)(ws);                  // 67,108,864 B
  unsigned short* qkv = (unsigned short*)(ws + 67108864);       // 201,326,592 B
  unsigned short* T   = (unsigned short*)(ws + 268435456);      // 67,108,864 B
  unsigned short* xb  = (unsigned short*)(ws + 335544320);      // 67,108,864 B
  unsigned short* wq  = (unsigned short*)(ws + 402653184);      // 393,216 B
  unsigned short* wp  = (unsigned short*)(ws + 403046400);      // 131,072 B
  unsigned short* w1  = (unsigned short*)(ws + 403177472);      // 524,288 B
  unsigned short* w2  = (unsigned short*)(ws + 403701760);      // 524,288 B
  float* btab         = (float*)(ws + 404226048);               // 524,288 B -> end 404,750,336
  unsigned short* attn_out = win;                // reuse (win dead after QKV)
  unsigned short* h2  = (unsigned short*)(ws);   // 268 MB (win+qkv regions, dead after proj)
  unsigned short* tn  = (unsigned short*)d_out;  // 67 MB scratch inside d_out (overwritten by FC2)

  if (ws_size < 404750336ull) return;  // workspace too small: fail loudly (poison stays)

  swin_cvt_all<<<3072, 256, 0, stream>>>(qkvw, projw, fc1w, fc2w, wq, wp, w1, w2);
  swin_btab<<<512, 256, 0, stream>>>(relb, btab);
  swin_ln1win<<<1024, 256, 0, stream>>>(x, ln1w, ln1b, win, xb);
  swin_gemm<0, 256><<<1536, 512, 0, stream>>>(win, wq, qkvb, qkv, nullptr, 131072, 768);
  swin_attn<<<4096, 256, 0, stream>>>(qkv, btab, attn_out);
  swin_gemm<1, 256><<<512, 512, 0, stream>>>(attn_out, wp, projb, T, xb, 131072, 256,
                                             ln2w, ln2b, tn);
  swin_gemm<2, 256><<<2048, 512, 0, stream>>>(tn, w1, fc1b, h2, nullptr, 131072, 1024);
  swin_gemm<3, 1024><<<512, 512, 0, stream>>>(h2, w2, fc2b, d_out, T, 131072, 256);
}